// Round 1
// baseline (229.741 us; speedup 1.0000x reference)
//
#include <hip/hip_runtime.h>
#include <cstdint>
#include <cmath>

#define NROWS 8192
#define KDIM  512            // elements; also bytes/row in fp8

typedef int    i32x4  __attribute__((ext_vector_type(4)));
typedef int    i32x8  __attribute__((ext_vector_type(8)));
typedef float  f32x16 __attribute__((ext_vector_type(16)));
typedef unsigned char u8;

#define AS1(p) ((const __attribute__((address_space(1))) void*)(p))
#define AS3(p) ((__attribute__((address_space(3))) void*)(p))

// contributing gemm blocks: pos upper-tri 1056 + neg 2048
#define TOTAL_BLOCKS 3104u

// --- Kernel 1: row L2-normalize fp32 -> fp8 e4m3 (OCP, HW cvt), one wave/row.
// zi rows [0,8192), zj rows [8192,16384). Also zeroes the 128 accumulator slots
// and the last-block counter (finalize is now fused into the gemm kernel).
__global__ __launch_bounds__(256) void nrm_kernel(const float* __restrict__ zi,
                                                  const float* __restrict__ zj,
                                                  u8* __restrict__ out,
                                                  double* __restrict__ acc,
                                                  unsigned* __restrict__ cnt) {
    if (blockIdx.x == 0) {
        if (threadIdx.x < 128) acc[threadIdx.x] = 0.0;
        if (threadIdx.x == 128) *cnt = 0u;
    }
    const int wave = threadIdx.x >> 6;
    const int lane = threadIdx.x & 63;
    const int row  = blockIdx.x * 4 + wave;            // 0..16383
    const float* src = (row < NROWS) ? zi + (size_t)row * KDIM
                                     : zj + (size_t)(row - NROWS) * KDIM;
    float4 a = ((const float4*)src)[lane];
    float4 b = ((const float4*)src)[lane + 64];
    float ss = a.x*a.x + a.y*a.y + a.z*a.z + a.w*a.w
             + b.x*b.x + b.y*b.y + b.z*b.z + b.w*b.w;
    #pragma unroll
    for (int off = 32; off >= 1; off >>= 1) ss += __shfl_xor(ss, off, 64);
    const float inv = 1.0f / fmaxf(sqrtf(ss), 1e-12f);
    int p0 = 0, p1 = 0;
    p0 = __builtin_amdgcn_cvt_pk_fp8_f32(a.x * inv, a.y * inv, p0, false);
    p0 = __builtin_amdgcn_cvt_pk_fp8_f32(a.z * inv, a.w * inv, p0, true);
    p1 = __builtin_amdgcn_cvt_pk_fp8_f32(b.x * inv, b.y * inv, p1, false);
    p1 = __builtin_amdgcn_cvt_pk_fp8_f32(b.z * inv, b.w * inv, p1, true);
    int* dst = (int*)(out + (size_t)row * KDIM);
    dst[lane]      = p0;
    dst[lane + 64] = p1;
}

// --- Kernel 2: fused MX-fp8 A*B^T -> exp(10*dot) -> global sum -> (last block) loss.
// R12 structural change: T3+T4 pipeline. Same 48 KB LDS as R11, but the two
// 24 KB halves are now a 2-deep double buffer over BK=64 K-steps instead of the
// two k-halves of a BK=128 step. Prologue stages tiles 0 and 1; the main loop
// waits s_waitcnt vmcnt(6) (tile t complete, tile t+1's 6 loads IN FLIGHT across
// the raw s_barrier — never drains to 0 until the final step), reads fragments,
// lgkmcnt(0)+sched_barrier(0), barrier #2 (all waves done reading buf[cur]),
// then stages tile t+2 into buf[cur] and runs 8 MFMAs under setprio(1) (T5 —
// pays now that a phase split exists). This removes the per-K-step full
// vmcnt(0) drain that capped the old structure at ~25% MfmaUtil.
// LDS XOR-swizzle unchanged (verified R2-R11, absmax 0): region = 32 rows x
// 64 B; chunk (r,b) at p = r*4 + (b ^ ((r>>1)&3)); staging inverse
// b = (lane&3)^((lane>>3)&3). Triangle skip unchanged. Finalize fused: last
// contributing block (device-scope atomic counter) reduces the 128 acc slots
// and writes the loss — one fewer launch in the graph.
__global__ __launch_bounds__(256, 2) void gemm_exp_reduce(const u8* __restrict__ A,
                                                          const u8* __restrict__ B,
                                                          double* __restrict__ acc,
                                                          unsigned* __restrict__ cnt,
                                                          float* __restrict__ out) {
    const int bx = blockIdx.x, by = blockIdx.y;
    const bool pos = (bx < 64);
    if (pos && bx < 2 * by) return;   // strict lower-tri pos block: mirror elsewhere

    __shared__ u8 lA[2][256 * 64];   // 2 pipeline bufs x 16 KB (8 regions of 32r x 64B)
    __shared__ u8 lB[2][128 * 64];   // 2 pipeline bufs x 8 KB  (4 regions)
    __shared__ float red[4];
    __shared__ double dred[2];
    __shared__ unsigned amLast;

    const int tid  = threadIdx.x;
    const int lane = tid & 63;
    const int wave = tid >> 6;
    const int m0   = by * 256;
    const int n0   = bx * 128;
    const int wm   = (wave >> 1) * 128;
    const int wn   = (wave & 1) * 64;

    f32x16 accf[4][2];
    #pragma unroll
    for (int i = 0; i < 4; ++i)
        #pragma unroll
        for (int j = 0; j < 2; ++j)
            #pragma unroll
            for (int r = 0; r < 16; ++r)
                accf[i][j][r] = 0.f;

    // staging (layout verified R2-R11): 16-row chunks of 1024 B per k-step.
    // A: wave does chunks wave*4..+3; B: wave*2..+1.
    // lane: global row = chunk*16 + (lane>>2), 16B-col bsw = (lane&3)^((lane>>3)&3).
    const int bsw = (lane & 3) ^ ((lane >> 3) & 3);
    const u8* gA0 = A + (size_t)(m0 + wave * 64 + (lane >> 2)) * KDIM + bsw * 16;
    const u8* gB0 = B + (size_t)(n0 + wave * 32 + (lane >> 2)) * KDIM + bsw * 16;
    const int ldsA = wave * 4096 + lane * 16;
    const int ldsB = wave * 2048 + lane * 16;

    // stage one BK=64 k-slice (6 x global_load_lds dwordx4 per thread)
    auto stage = [&](int t, int buf) {
        const size_t kb = (size_t)t * 64;
        #pragma unroll
        for (int c = 0; c < 4; ++c)
            __builtin_amdgcn_global_load_lds(AS1(gA0 + kb + (size_t)c * 16 * KDIM),
                                             AS3(&lA[buf][ldsA + c * 1024]), 16, 0, 0);
        #pragma unroll
        for (int c = 0; c < 2; ++c)
            __builtin_amdgcn_global_load_lds(AS1(gB0 + kb + (size_t)c * 16 * KDIM),
                                             AS3(&lB[buf][ldsB + c * 1024]), 16, 0, 0);
    };

    // fragment read: lane row r=lane&31, k-half-of-64 q=lane>>5 (chunks 2q,2q+1);
    // swizzled position p = r*4 + ((2q) ^ ((r>>1)&3)); partner chunk at ^16.
    const int r_  = lane & 31;
    const int q_  = lane >> 5;
    const int p16 = (r_ * 4 + ((2 * q_) ^ ((r_ >> 1) & 3))) * 16;
    const int aT0 = (wave >> 1) * 4;   // A regions aT0..aT0+3 (128 rows)
    const int bT0 = (wave & 1) * 2;    // B regions bT0..bT0+1 (64 rows)

    stage(0, 0);                       // 6 loads in flight
    stage(1, 1);                       // 12 loads in flight

    #pragma unroll
    for (int t = 0; t < 8; ++t) {      // 8 K-steps of 64
        const int cur = t & 1;
        // tile t landed; tile t+1's 6 loads stay in flight across the barrier
        if (t < 7) asm volatile("s_waitcnt vmcnt(6)" ::: "memory");
        else       asm volatile("s_waitcnt vmcnt(0)" ::: "memory");
        __builtin_amdgcn_s_barrier();              // all waves see buf[cur] ready

        i32x8 af[4], bfr[2];
        #pragma unroll
        for (int mi = 0; mi < 4; ++mi) {
            const int off = (aT0 + mi) * 2048 + p16;
            *(i32x4*)&af[mi]       = *(const i32x4*)&lA[cur][off];
            *((i32x4*)&af[mi] + 1) = *(const i32x4*)&lA[cur][off ^ 16];
        }
        #pragma unroll
        for (int ni = 0; ni < 2; ++ni) {
            const int off = (bT0 + ni) * 2048 + p16;
            *(i32x4*)&bfr[ni]       = *(const i32x4*)&lB[cur][off];
            *((i32x4*)&bfr[ni] + 1) = *(const i32x4*)&lB[cur][off ^ 16];
        }
        asm volatile("s_waitcnt lgkmcnt(0)" ::: "memory");
        __builtin_amdgcn_sched_barrier(0);
        __builtin_amdgcn_s_barrier();              // all waves done reading buf[cur]

        if (t + 2 < 8) stage(t + 2, cur);          // refill freed buffer; MFMAs hide it

        __builtin_amdgcn_s_setprio(1);
        #pragma unroll
        for (int mi = 0; mi < 4; ++mi)
            #pragma unroll
            for (int ni = 0; ni < 2; ++ni)
                accf[mi][ni] = __builtin_amdgcn_mfma_scale_f32_32x32x64_f8f6f4(
                    af[mi], bfr[ni], accf[mi][ni],
                    0, 0,                 // cbsz=fp8(e4m3), blgp=fp8(e4m3)
                    0, 0x7f7f7f7f,        // scale_a: every byte = 2^0
                    0, 0x7f7f7f7f);       // scale_b
        __builtin_amdgcn_s_setprio(0);
    }

    // epilogue: exp(10*d) = exp2(d*10/ln2); near-diag pos blocks skip rr==cc
    const float LOG2E10 = 14.4269504088896341f;
    float part = 0.f;
    if (pos && (bx >> 1) == by) {
        #pragma unroll
        for (int mi = 0; mi < 4; ++mi)
            #pragma unroll
            for (int ni = 0; ni < 2; ++ni)
                #pragma unroll
                for (int r = 0; r < 16; ++r) {
                    // C/D 32x32: col=lane&31, row=(r&3)+8*(r>>2)+4*(lane>>5)
                    int rr = m0 + wm + mi * 32 + ((r & 3) + 8 * (r >> 2) + 4 * q_);
                    int cc = n0 + wn + ni * 32 + r_;
                    if (rr != cc) part += exp2f(accf[mi][ni][r] * LOG2E10);
                }
    } else {
        #pragma unroll
        for (int mi = 0; mi < 4; ++mi)
            #pragma unroll
            for (int ni = 0; ni < 2; ++ni)
                #pragma unroll
                for (int r = 0; r < 16; ++r)
                    part += exp2f(accf[mi][ni][r] * LOG2E10);
    }

    #pragma unroll
    for (int off = 32; off >= 1; off >>= 1) part += __shfl_xor(part, off, 64);
    if (lane == 0) red[wave] = part;
    __syncthreads();
    if (tid == 0) {
        double s = (double)red[0] + (double)red[1] + (double)red[2] + (double)red[3];
        if (pos && bx >= 2 * by + 2) s *= 2.0;   // stands in for its skipped mirror
        atomicAdd(&acc[(pos ? 0 : 64) + (((unsigned)bx * 7 + (unsigned)by) & 63)], s);
        __threadfence();
        unsigned prev = __hip_atomic_fetch_add(cnt, 1u, __ATOMIC_ACQ_REL,
                                               __HIP_MEMORY_SCOPE_AGENT);
        amLast = (prev == TOTAL_BLOCKS - 1u) ? 1u : 0u;
    }
    __syncthreads();

    // fused finalize: last contributing block reduces the 128 slots.
    // slots 0..63 = pos partials (wave 0), 64..127 = neg partials (wave 1).
    if (amLast) {
        double v = 0.0;
        if (tid < 128)
            v = __hip_atomic_load(&acc[tid], __ATOMIC_ACQUIRE, __HIP_MEMORY_SCOPE_AGENT);
        #pragma unroll
        for (int off = 32; off >= 1; off >>= 1) v += __shfl_xor(v, off, 64);
        if (tid == 0)  dred[0] = v;   // pos sum
        if (tid == 64) dred[1] = v;   // neg sum
        __syncthreads();
        if (tid == 0) {
            double p = dred[0] + 8192.0 * exp(10.0);   // exact pos diagonal
            out[0] = (float)log1p(dred[1] / p);
        }
    }
}

extern "C" void kernel_launch(void* const* d_in, const int* in_sizes, int n_in,
                              void* d_out, int out_size, void* d_ws, size_t ws_size,
                              hipStream_t stream) {
    const float* zi = (const float*)d_in[0];
    const float* zj = (const float*)d_in[1];
    u8* nrm = (u8*)d_ws;                                      // [16384][512] fp8 = 8 MB
    double* acc = (double*)((char*)d_ws + (size_t)16384 * 512);
    unsigned* cnt = (unsigned*)(acc + 128);

    nrm_kernel<<<4096, 256, 0, stream>>>(zi, zj, nrm, acc, cnt);
    dim3 grid(128, 32);   // x: 16384/128 n-tiles, y: 8192/256 m-tiles
    gemm_exp_reduce<<<grid, 256, 0, stream>>>(nrm, nrm, acc, cnt, (float*)d_out);
}